// Round 8
// baseline (94.356 us; speedup 1.0000x reference)
//
#include <hip/hip_runtime.h>
#include <hip/hip_bf16.h>

#define B_TOT  1024
#define IN_DIM 512
#define C_DIM  128
#define HID    128
#define EMB    32
#define BK     32
#define NKT    (IN_DIM / BK)   // 16

// workspace layout (ushort indices) — all operands FRAGMENT-PACKED:
//  W1: ws[pair*65536 + kt*4096 + nfrag*512 + lane*8 + kin]
//      lane = lkg*16 + (h&15), holds W1[k0+lkg*8+kin][h]  (kt: 32-k chunk, nfrag: 16-h)
//  W2: WS_W2_OFF + pair*4096 + k2*1024 + ei*512 + lane*8 + kin
//      lane = lkg*16 + (e&15), holds W2[k2*32+lkg*8+kin][e]
//  X : WS_X_OFF + btile*65536 + kt*4096 + mfrag*512 + lane*8 + kin
//      lane = lkg*16 + (row&15), holds x[row][kt*32+lkg*8+kin]
#define WS_W1_STRIDE 65536ull
#define WS_W2_OFF    16777216ull
#define WS_X_OFF     17825792ull
#define WS_NEEDED_B  36700160ull               // bytes

using bf16x8 = __attribute__((ext_vector_type(8))) short;
using f32x4  = __attribute__((ext_vector_type(4))) float;

__device__ __forceinline__ unsigned short f2b(float f) {
    union { __hip_bfloat16 h; unsigned short u; } cv;
    cv.h = __float2bfloat16(f);
    return cv.u;
}
__device__ __forceinline__ unsigned int pack2(float a, float b) {
    return (unsigned int)f2b(a) | ((unsigned int)f2b(b) << 16);
}
__device__ __forceinline__ unsigned long long pack4(float a, float b, float c, float d) {
    return (unsigned long long)pack2(a, b) | ((unsigned long long)pack2(c, d) << 32);
}
__device__ __forceinline__ bf16x8 ld16(const unsigned short* p) {
    return *(const bf16x8*)p;
}

// ============================ prepass ============================
// 1024 blocks x 256 thr. pair = blk>>2, quarter = blk&3; x-row = blk.
__global__ __launch_bounds__(256) void prepass(
    const float* __restrict__ x,
    const float* __restrict__ pW1, const float* __restrict__ pW2,
    const float* __restrict__ nW1, const float* __restrict__ nW2,
    unsigned short* __restrict__ ws)
{
    __shared__ unsigned short img[4096];   // 8 KB
    const int blk     = blockIdx.x;
    const int pair    = blk >> 2;          // bank*128 + c
    const int quarter = blk & 3;
    const int bank    = pair >> 7;
    const int c       = pair & 127;
    const int t       = threadIdx.x;

    const float* W1c = (bank ? nW1 : pW1) + (size_t)c * IN_DIM * HID;
    const float* W2c = (bank ? nW2 : pW2) + (size_t)c * HID * EMB;

    // ---- W2 (quarter 0 only): frag-pack ----
    if (quarter == 0) {
        int e0 = (t & 7) * 4, h0 = (t >> 3) * 4;   // h0: 0..124 (4-aligned)
        const float* src = &W2c[(size_t)h0 * EMB + e0];
        f32x4 L0 = *(const f32x4*)(src + 0 * EMB);
        f32x4 L1 = *(const f32x4*)(src + 1 * EMB);
        f32x4 L2 = *(const f32x4*)(src + 2 * EMB);
        f32x4 L3 = *(const f32x4*)(src + 3 * EMB);
        unsigned short* dst = ws + WS_W2_OFF + (size_t)pair * 4096;
#pragma unroll
        for (int j = 0; j < 4; ++j) {
            int e = e0 + j;
            // element (e, h0..h0+3): k2=h>>5, lkg=(h&31)>>3, kin=h&7 contiguous
            int idx = (h0 >> 5) * 1024 + (e >> 4) * 512 +
                      ((((h0 & 31) >> 3) * 16 + (e & 15)) * 8) + (h0 & 7);
            *(unsigned long long*)&dst[idx] = pack4(L0[j], L1[j], L2[j], L3[j]);
        }
    }

    // ---- W1: four 32-k chunks per block, frag-packed via img ----
#pragma unroll
    for (int q = 0; q < 4; ++q) {
        const int kt = quarter * 4 + q;
        const float* Wk = W1c + (size_t)kt * BK * HID;
        {
            int k0 = (t >> 5) * 4;       // 0..28
            int h0 = (t & 31) * 4;       // 0..124
            const float* src = &Wk[(size_t)k0 * HID + h0];
            f32x4 L0 = *(const f32x4*)(src + 0 * HID);
            f32x4 L1 = *(const f32x4*)(src + 1 * HID);
            f32x4 L2 = *(const f32x4*)(src + 2 * HID);
            f32x4 L3 = *(const f32x4*)(src + 3 * HID);
#pragma unroll
            for (int j = 0; j < 4; ++j) {
                int h = h0 + j;
                // element (h, k0..k0+3): nfrag=h>>4, lane=lkg*16+(h&15), kin=k&7
                int idx = (h >> 4) * 512 +
                          (((k0 >> 3) * 16 + (h & 15)) * 8) + (k0 & 7);
                *(unsigned long long*)&img[idx] = pack4(L0[j], L1[j], L2[j], L3[j]);
            }
        }
        __syncthreads();
        unsigned short* dst = ws + (size_t)pair * WS_W1_STRIDE + (size_t)kt * 4096;
        *(bf16x8*)&dst[t * 16]     = *(const bf16x8*)&img[t * 16];
        *(bf16x8*)&dst[t * 16 + 8] = *(const bf16x8*)&img[t * 16 + 8];
        __syncthreads();
    }

    // ---- x: one row per block, frag-packed (8B scatter, one-time cost) ----
    {
        const int row = blk;              // 0..1023
        if (t < 128) {
            int k0 = t * 4;
            f32x4 v = *(const f32x4*)&x[(size_t)row * IN_DIM + k0];
            size_t idx = WS_X_OFF + (size_t)(row >> 7) * 65536 +
                         (size_t)(k0 >> 5) * 4096 + (size_t)((row & 127) >> 4) * 512 +
                         ((((k0 & 31) >> 3) * 16 + (row & 15)) * 8) + (k0 & 7);
            *(unsigned long long*)&ws[idx] = pack4(v[0], v[1], v[2], v[3]);
        }
    }
}

// ============================ main ============================
// 2048 blocks, 256 thr. K-loop: NO LDS, NO BARRIERS — both operands stream
// global(ws)->VGPR as fragment-packed coalesced dwordx4 loads, 3-deep reg
// pipeline, waves fully independent. LDS (32 KB) only for the Hs/GEMM2 tail.
__global__ __launch_bounds__(256, 2) void bank_main(
    const float* __restrict__ pb1, const float* __restrict__ pb2,
    const float* __restrict__ nb1, const float* __restrict__ nb2,
    const unsigned short* __restrict__ ws,
    float* __restrict__ out)
{
    __shared__ unsigned short smem[16384];   // 32 KB: Hs only

    const int p     = blockIdx.x;
    const int xcd   = p & 7;
    const int rank  = p >> 3;             // 0..255
    const int c     = xcd * 16 + (rank & 15);
    const int btile = (rank >> 4) & 7;
    const int bank  = rank >> 7;
    const int pair  = bank * 128 + c;
    const int bbase = btile * 128;

    const int t    = threadIdx.x;
    const int wave = t >> 6;
    const int lane = t & 63;
    const int lr   = lane & 15;
    const int lkg  = lane >> 4;
    const int wm   = wave >> 1;
    const int wn   = wave & 1;

    // per-wave fragment base pointers (lane folded in)
    const unsigned short* aws = ws + WS_X_OFF + (size_t)btile * 65536 +
                                (size_t)(wm * 4) * 512 + lane * 8;
    const unsigned short* bws = ws + (size_t)pair * WS_W1_STRIDE +
                                (size_t)(wn * 4) * 512 + lane * 8;

    f32x4 acc[4][4];
#pragma unroll
    for (int mi = 0; mi < 4; ++mi)
#pragma unroll
        for (int ni = 0; ni < 4; ++ni) acc[mi][ni] = (f32x4){0.f, 0.f, 0.f, 0.f};

    bf16x8 A0[4], A1[4], A2[4], B0[4], B1[4], B2[4];

#define LOADK(KT, AB, BB)                                                       \
    {                                                                           \
        const unsigned short* ab = aws + (KT) * 4096;                           \
        const unsigned short* bb = bws + (KT) * 4096;                           \
        AB[0] = ld16(ab);        AB[1] = ld16(ab + 512);                        \
        AB[2] = ld16(ab + 1024); AB[3] = ld16(ab + 1536);                       \
        BB[0] = ld16(bb);        BB[1] = ld16(bb + 512);                        \
        BB[2] = ld16(bb + 1024); BB[3] = ld16(bb + 1536);                       \
    }
#define MM(AB, BB)                                                              \
    {                                                                           \
        __builtin_amdgcn_s_setprio(1);                                          \
        _Pragma("unroll")                                                       \
        for (int mi = 0; mi < 4; ++mi)                                          \
            _Pragma("unroll")                                                   \
            for (int ni = 0; ni < 4; ++ni)                                      \
                acc[mi][ni] = __builtin_amdgcn_mfma_f32_16x16x32_bf16(          \
                    AB[mi], BB[ni], acc[mi][ni], 0, 0, 0);                      \
        __builtin_amdgcn_s_setprio(0);                                          \
    }

    LOADK(0, A0, B0)
    LOADK(1, A1, B1)
    LOADK(2, A2, B2)  MM(A0, B0)    // step 0
    LOADK(3, A0, B0)  MM(A1, B1)    // step 1
    LOADK(4, A1, B1)  MM(A2, B2)    // step 2
    LOADK(5, A2, B2)  MM(A0, B0)    // step 3
    LOADK(6, A0, B0)  MM(A1, B1)    // step 4
    LOADK(7, A1, B1)  MM(A2, B2)    // step 5
    LOADK(8, A2, B2)  MM(A0, B0)    // step 6
    LOADK(9, A0, B0)  MM(A1, B1)    // step 7
    LOADK(10, A1, B1) MM(A2, B2)    // step 8
    LOADK(11, A2, B2) MM(A0, B0)    // step 9
    LOADK(12, A0, B0) MM(A1, B1)    // step 10
    LOADK(13, A1, B1) MM(A2, B2)    // step 11
    LOADK(14, A2, B2) MM(A0, B0)    // step 12
    LOADK(15, A0, B0) MM(A1, B1)    // step 13
    MM(A2, B2)                      // step 14
    MM(A0, B0)                      // step 15
#undef LOADK
#undef MM

    // biases
    const float* b1c = (bank ? nb1 : pb1) + c * HID;
    const float* b2c = (bank ? nb2 : pb2) + c * EMB;
    float b1v[4];
#pragma unroll
    for (int ni = 0; ni < 4; ++ni) b1v[ni] = b1c[wn * 64 + ni * 16 + lr];

    // epilogue1: bias+relu -> Hs in LDS (swizzled [r][h], kg ^= r&7)
#pragma unroll
    for (int mi = 0; mi < 4; ++mi) {
        int row0 = wm * 64 + mi * 16 + lkg * 4;
#pragma unroll
        for (int ni = 0; ni < 4; ++ni) {
            int col = wn * 64 + ni * 16 + lr;
            int kgH = col >> 3, kin = col & 7;
#pragma unroll
            for (int j = 0; j < 4; ++j) {
                int r = row0 + j;
                float v = fmaxf(acc[mi][ni][j] + b1v[ni], 0.f);
                smem[r * 128 + ((kgH ^ (r & 7)) << 3) + kin] = f2b(v);
            }
        }
    }
    __syncthreads();

    // W2 fragments (frag-packed, coalesced)
    const unsigned short* w2base = ws + WS_W2_OFF + (size_t)pair * 4096 + lane * 8;
    bf16x8 w2f[2][4];
#pragma unroll
    for (int k2 = 0; k2 < 4; ++k2)
#pragma unroll
        for (int ei = 0; ei < 2; ++ei)
            w2f[ei][k2] = ld16(w2base + k2 * 1024 + ei * 512);
    float b2v[2];
#pragma unroll
    for (int ei = 0; ei < 2; ++ei) b2v[ei] = b2c[ei * 16 + lr];

    // GEMM2: M=128, N=32, K=128; each wave 32 rows
    f32x4 acc2[2][2];
#pragma unroll
    for (int m2 = 0; m2 < 2; ++m2)
#pragma unroll
        for (int ei = 0; ei < 2; ++ei) acc2[m2][ei] = (f32x4){0.f, 0.f, 0.f, 0.f};
    const int rb = wave * 32;
#pragma unroll
    for (int k2 = 0; k2 < 4; ++k2) {
        int kg = k2 * 4 + lkg;
        bf16x8 a2[2];
#pragma unroll
        for (int m2 = 0; m2 < 2; ++m2) {
            int r = rb + m2 * 16 + lr;
            a2[m2] = ld16(&smem[r * 128 + ((kg ^ (r & 7)) << 3)]);
        }
#pragma unroll
        for (int m2 = 0; m2 < 2; ++m2)
#pragma unroll
            for (int ei = 0; ei < 2; ++ei)
                acc2[m2][ei] = __builtin_amdgcn_mfma_f32_16x16x32_bf16(
                    a2[m2], w2f[ei][k2], acc2[m2][ei], 0, 0, 0);
    }

    float* outb = out + (size_t)bank * B_TOT * EMB * C_DIM;
#pragma unroll
    for (int m2 = 0; m2 < 2; ++m2) {
#pragma unroll
        for (int ei = 0; ei < 2; ++ei) {
            int e = ei * 16 + lr;
#pragma unroll
            for (int j = 0; j < 4; ++j) {
                int brow = bbase + rb + m2 * 16 + lkg * 4 + j;
                outb[((size_t)brow * EMB + e) * C_DIM + c] = acc2[m2][ei][j] + b2v[ei];
            }
        }
    }
}

// ===================== fallback (round-1 kernel, known-good) =====================
#define XS_LD 68
#define W1_LD 68
#define HS_LD 132
#define W2_LD 132
__device__ __forceinline__ bf16x8 load8u(const unsigned short* p) {
    union { unsigned long long q[2]; bf16x8 v; } u;
    u.q[0] = *(const unsigned long long*)(p);
    u.q[1] = *(const unsigned long long*)(p + 4);
    return u.v;
}
__global__ __launch_bounds__(256, 2) void bank_fallback(
    const float* __restrict__ x,
    const float* __restrict__ pW1, const float* __restrict__ pb1,
    const float* __restrict__ pW2, const float* __restrict__ pb2,
    const float* __restrict__ nW1, const float* __restrict__ nb1,
    const float* __restrict__ nW2, const float* __restrict__ nb2,
    float* __restrict__ out)
{
    __shared__ unsigned short Xs [128][XS_LD];
    __shared__ unsigned short W1T[HID][W1_LD];
    __shared__ unsigned short Hs [128][HS_LD];
    __shared__ unsigned short W2T[EMB][W2_LD];
    int p = blockIdx.x;
    int xcd = p & 7, rank = p >> 3;
    int c = xcd * 16 + (rank & 15);
    int btile = (rank >> 4) & 7;
    int bank = rank >> 7;
    int bbase = btile * 128;
    const float* W1c = (bank ? nW1 : pW1) + (size_t)c * IN_DIM * HID;
    const float* b1c = (bank ? nb1 : pb1) + c * HID;
    const float* W2c = (bank ? nW2 : pW2) + (size_t)c * HID * EMB;
    const float* b2c = (bank ? nb2 : pb2) + c * EMB;
    float* outb = out + (size_t)bank * B_TOT * EMB * C_DIM;
    int t = threadIdx.x, wave = t >> 6, lane = t & 63;
    int lr = lane & 15, lkg = lane >> 4, wm = wave >> 1, wn = wave & 1;
    {
        int e0 = (t & 7) * 4, h0 = (t >> 3) * 4;
        f32x4 L0 = *(const f32x4*)&W2c[(h0 + 0) * EMB + e0];
        f32x4 L1 = *(const f32x4*)&W2c[(h0 + 1) * EMB + e0];
        f32x4 L2 = *(const f32x4*)&W2c[(h0 + 2) * EMB + e0];
        f32x4 L3 = *(const f32x4*)&W2c[(h0 + 3) * EMB + e0];
#pragma unroll
        for (int j = 0; j < 4; ++j)
            *(unsigned long long*)&W2T[e0 + j][h0] = pack4(L0[j], L1[j], L2[j], L3[j]);
    }
    float b1v[4];
#pragma unroll
    for (int ni = 0; ni < 4; ++ni) b1v[ni] = b1c[wn * 64 + ni * 16 + lr];
    float b2v[2];
#pragma unroll
    for (int ei = 0; ei < 2; ++ei) b2v[ei] = b2c[ei * 16 + lr];
    f32x4 acc[4][4];
#pragma unroll
    for (int mi = 0; mi < 4; ++mi)
#pragma unroll
        for (int ni = 0; ni < 4; ++ni) acc[mi][ni] = (f32x4){0.f, 0.f, 0.f, 0.f};
    for (int kt = 0; kt < 8; ++kt) {
        int kb = kt * 64;
#pragma unroll
        for (int w8 = 0; w8 < 8; ++w8) {
            int f = w8 * 256 + t;
            int row = f >> 4, col = (f & 15) * 4;
            f32x4 v = *(const f32x4*)&x[(size_t)(bbase + row) * IN_DIM + kb + col];
            *(unsigned long long*)&Xs[row][col] = pack4(v[0], v[1], v[2], v[3]);
        }
#pragma unroll
        for (int g = 0; g < 2; ++g) {
            int s = g * 256 + t;
            int k0 = (s >> 5) * 4, h0 = (s & 31) * 4;
            const float* src = &W1c[(size_t)(kb + k0) * HID + h0];
            f32x4 L0 = *(const f32x4*)(src + 0 * HID);
            f32x4 L1 = *(const f32x4*)(src + 1 * HID);
            f32x4 L2 = *(const f32x4*)(src + 2 * HID);
            f32x4 L3 = *(const f32x4*)(src + 3 * HID);
#pragma unroll
            for (int j = 0; j < 4; ++j)
                *(unsigned long long*)&W1T[h0 + j][k0] = pack4(L0[j], L1[j], L2[j], L3[j]);
        }
        __syncthreads();
#pragma unroll
        for (int ki = 0; ki < 2; ++ki) {
            int kcol = ki * 32 + lkg * 8;
            bf16x8 af[4], bfr[4];
#pragma unroll
            for (int mi = 0; mi < 4; ++mi) af[mi] = load8u(&Xs[wm * 64 + mi * 16 + lr][kcol]);
#pragma unroll
            for (int ni = 0; ni < 4; ++ni) bfr[ni] = load8u(&W1T[wn * 64 + ni * 16 + lr][kcol]);
#pragma unroll
            for (int mi = 0; mi < 4; ++mi)
#pragma unroll
                for (int ni = 0; ni < 4; ++ni)
                    acc[mi][ni] = __builtin_amdgcn_mfma_f32_16x16x32_bf16(
                        af[mi], bfr[ni], acc[mi][ni], 0, 0, 0);
        }
        __syncthreads();
    }
#pragma unroll
    for (int mi = 0; mi < 4; ++mi) {
        int row = wm * 64 + mi * 16 + lkg * 4;
#pragma unroll
        for (int ni = 0; ni < 4; ++ni) {
            int col = wn * 64 + ni * 16 + lr;
#pragma unroll
            for (int j = 0; j < 4; ++j)
                Hs[row + j][col] = f2b(fmaxf(acc[mi][ni][j] + b1v[ni], 0.f));
        }
    }
    __syncthreads();
    f32x4 acc2[2][2];
#pragma unroll
    for (int m2 = 0; m2 < 2; ++m2)
#pragma unroll
        for (int ei = 0; ei < 2; ++ei) acc2[m2][ei] = (f32x4){0.f, 0.f, 0.f, 0.f};
    int rb = wave * 32;
#pragma unroll
    for (int k2 = 0; k2 < 4; ++k2) {
        int kcol = k2 * 32 + lkg * 8;
        bf16x8 a2[2], b2f[2];
#pragma unroll
        for (int m2 = 0; m2 < 2; ++m2) a2[m2] = load8u(&Hs[rb + m2 * 16 + lr][kcol]);
#pragma unroll
        for (int ei = 0; ei < 2; ++ei) b2f[ei] = load8u(&W2T[ei * 16 + lr][kcol]);
#pragma unroll
        for (int m2 = 0; m2 < 2; ++m2)
#pragma unroll
            for (int ei = 0; ei < 2; ++ei)
                acc2[m2][ei] = __builtin_amdgcn_mfma_f32_16x16x32_bf16(
                    a2[m2], b2f[ei], acc2[m2][ei], 0, 0, 0);
    }
#pragma unroll
    for (int m2 = 0; m2 < 2; ++m2)
#pragma unroll
        for (int ei = 0; ei < 2; ++ei) {
            int e = ei * 16 + lr;
#pragma unroll
            for (int j = 0; j < 4; ++j) {
                int brow = bbase + rb + m2 * 16 + lkg * 4 + j;
                outb[((size_t)brow * EMB + e) * C_DIM + c] = acc2[m2][ei][j] + b2v[ei];
            }
        }
}

extern "C" void kernel_launch(void* const* d_in, const int* in_sizes, int n_in,
                              void* d_out, int out_size, void* d_ws, size_t ws_size,
                              hipStream_t stream) {
    const float* x   = (const float*)d_in[0];
    const float* pW1 = (const float*)d_in[1];
    const float* pb1 = (const float*)d_in[2];
    const float* pW2 = (const float*)d_in[3];
    const float* pb2 = (const float*)d_in[4];
    const float* nW1 = (const float*)d_in[5];
    const float* nb1 = (const float*)d_in[6];
    const float* nW2 = (const float*)d_in[7];
    const float* nb2 = (const float*)d_in[8];
    float* out = (float*)d_out;

    if (ws_size >= WS_NEEDED_B) {
        unsigned short* ws = (unsigned short*)d_ws;
        prepass<<<dim3(1024), dim3(256), 0, stream>>>(x, pW1, pW2, nW1, nW2, ws);
        bank_main<<<dim3(2048), dim3(256), 0, stream>>>(pb1, pb2, nb1, nb2, ws, out);
    } else {
        bank_fallback<<<dim3(2048), dim3(256), 0, stream>>>(
            x, pW1, pb1, pW2, pb2, nW1, nb1, nW2, nb2, out);
    }
}

// Round 9
// 90.804 us; speedup vs baseline: 1.0391x; 1.0391x over previous
//
#include <hip/hip_runtime.h>
#include <hip/hip_bf16.h>

#define B_TOT  1024
#define IN_DIM 512
#define C_DIM  128
#define HID    128
#define EMB    32
#define BK     32
#define NKT    (IN_DIM / BK)   // 16

// workspace layout (ushort indices) — all operands FRAGMENT-PACKED:
//  W1: ws[pair*65536 + kt*4096 + nfrag*512 + lane*8 + kin]
//      lane = lkg*16 + (h&15), holds W1[k0+lkg*8+kin][h]
//  W2: WS_W2_OFF + pair*4096 + k2*1024 + ei*512 + lane*8 + kin
//  X : WS_X_OFF + rowblk128*65536 + kt*4096 + mfrag*512 + lane*8 + kin
//      lane = lkg*16 + (row&15), holds x[row][kt*32+lkg*8+kin]
#define WS_W1_STRIDE 65536ull
#define WS_W2_OFF    16777216ull
#define WS_X_OFF     17825792ull
#define WS_NEEDED_B  36700160ull               // bytes

using bf16x8 = __attribute__((ext_vector_type(8))) short;
using f32x4  = __attribute__((ext_vector_type(4))) float;

__device__ __forceinline__ unsigned short f2b(float f) {
    union { __hip_bfloat16 h; unsigned short u; } cv;
    cv.h = __float2bfloat16(f);
    return cv.u;
}
__device__ __forceinline__ unsigned int pack2(float a, float b) {
    return (unsigned int)f2b(a) | ((unsigned int)f2b(b) << 16);
}
__device__ __forceinline__ unsigned long long pack4(float a, float b, float c, float d) {
    return (unsigned long long)pack2(a, b) | ((unsigned long long)pack2(c, d) << 32);
}
__device__ __forceinline__ bf16x8 ld16(const unsigned short* p) {
    return *(const bf16x8*)p;
}

// ============================ prepass ============================
// 1024 blocks x 256 thr. pair = blk>>2, quarter = blk&3; x-row = blk.
__global__ __launch_bounds__(256) void prepass(
    const float* __restrict__ x,
    const float* __restrict__ pW1, const float* __restrict__ pW2,
    const float* __restrict__ nW1, const float* __restrict__ nW2,
    unsigned short* __restrict__ ws)
{
    __shared__ unsigned short img[4096];   // 8 KB
    const int blk     = blockIdx.x;
    const int pair    = blk >> 2;          // bank*128 + c
    const int quarter = blk & 3;
    const int bank    = pair >> 7;
    const int c       = pair & 127;
    const int t       = threadIdx.x;

    const float* W1c = (bank ? nW1 : pW1) + (size_t)c * IN_DIM * HID;
    const float* W2c = (bank ? nW2 : pW2) + (size_t)c * HID * EMB;

    // ---- W2 (quarter 0 only): frag-pack ----
    if (quarter == 0) {
        int e0 = (t & 7) * 4, h0 = (t >> 3) * 4;
        const float* src = &W2c[(size_t)h0 * EMB + e0];
        f32x4 L0 = *(const f32x4*)(src + 0 * EMB);
        f32x4 L1 = *(const f32x4*)(src + 1 * EMB);
        f32x4 L2 = *(const f32x4*)(src + 2 * EMB);
        f32x4 L3 = *(const f32x4*)(src + 3 * EMB);
        unsigned short* dst = ws + WS_W2_OFF + (size_t)pair * 4096;
#pragma unroll
        for (int j = 0; j < 4; ++j) {
            int e = e0 + j;
            int idx = (h0 >> 5) * 1024 + (e >> 4) * 512 +
                      ((((h0 & 31) >> 3) * 16 + (e & 15)) * 8) + (h0 & 7);
            *(unsigned long long*)&dst[idx] = pack4(L0[j], L1[j], L2[j], L3[j]);
        }
    }

    // ---- W1: four 32-k chunks per block, frag-packed via img ----
#pragma unroll
    for (int q = 0; q < 4; ++q) {
        const int kt = quarter * 4 + q;
        const float* Wk = W1c + (size_t)kt * BK * HID;
        {
            int k0 = (t >> 5) * 4;       // 0..28
            int h0 = (t & 31) * 4;       // 0..124
            const float* src = &Wk[(size_t)k0 * HID + h0];
            f32x4 L0 = *(const f32x4*)(src + 0 * HID);
            f32x4 L1 = *(const f32x4*)(src + 1 * HID);
            f32x4 L2 = *(const f32x4*)(src + 2 * HID);
            f32x4 L3 = *(const f32x4*)(src + 3 * HID);
#pragma unroll
            for (int j = 0; j < 4; ++j) {
                int h = h0 + j;
                int idx = (h >> 4) * 512 +
                          (((k0 >> 3) * 16 + (h & 15)) * 8) + (k0 & 7);
                *(unsigned long long*)&img[idx] = pack4(L0[j], L1[j], L2[j], L3[j]);
            }
        }
        __syncthreads();
        unsigned short* dst = ws + (size_t)pair * WS_W1_STRIDE + (size_t)kt * 4096;
        *(bf16x8*)&dst[t * 16]     = *(const bf16x8*)&img[t * 16];
        *(bf16x8*)&dst[t * 16 + 8] = *(const bf16x8*)&img[t * 16 + 8];
        __syncthreads();
    }

    // ---- x: one row per block, frag-packed (8B scatter, one-time cost) ----
    {
        const int row = blk;              // 0..1023
        if (t < 128) {
            int k0 = t * 4;
            f32x4 v = *(const f32x4*)&x[(size_t)row * IN_DIM + k0];
            size_t idx = WS_X_OFF + (size_t)(row >> 7) * 65536 +
                         (size_t)(k0 >> 5) * 4096 + (size_t)((row & 127) >> 4) * 512 +
                         ((((k0 & 31) >> 3) * 16 + (row & 15)) * 8) + (k0 & 7);
            *(unsigned long long*)&ws[idx] = pack4(v[0], v[1], v[2], v[3]);
        }
    }
}

// ============================ main ============================
// 1024 blocks x 256 thr. Block = 256 B-rows x 128 HID; wave = 64 rows x 128.
// K-loop: register double-buffer, 12 coalesced loads + 32 MFMA per step,
// ZERO LDS / ZERO barriers anywhere (GEMM2 rows are wave-private).
// Mapping: btile fastest -> same-W1 blocks concurrent on one XCD (L2 hits);
// 16 c's of each output line within one resident generation (write merge).
__global__ __launch_bounds__(256, 2) void bank_main(
    const float* __restrict__ pb1, const float* __restrict__ pb2,
    const float* __restrict__ nb1, const float* __restrict__ nb2,
    const unsigned short* __restrict__ ws,
    float* __restrict__ out)
{
    __shared__ unsigned short smem[32768];   // 64 KB Hs [256][128] swizzled

    const int p     = blockIdx.x;          // 0..1023
    const int xcd   = p & 7;
    const int rank  = p >> 3;              // 0..127
    const int btile = rank & 3;            // fast: W1-reuse concurrency
    const int c16   = (rank >> 2) & 15;
    const int bank  = rank >> 6;
    const int c     = xcd * 16 + c16;
    const int pair  = bank * 128 + c;
    const int bbase = btile * 256;

    const int t    = threadIdx.x;
    const int wave = t >> 6;
    const int lane = t & 63;
    const int lr   = lane & 15;
    const int lkg  = lane >> 4;

    // A: wave covers rows bbase + wave*64 .. +63
    const int rowblk = btile * 2 + (wave >> 1);
    const unsigned short* aws = ws + WS_X_OFF + (size_t)rowblk * 65536 +
                                (size_t)(wave & 1) * 2048 + lane * 8;
    const unsigned short* bws = ws + (size_t)pair * WS_W1_STRIDE + lane * 8;

    f32x4 acc[4][8];
#pragma unroll
    for (int mi = 0; mi < 4; ++mi)
#pragma unroll
        for (int ni = 0; ni < 8; ++ni) acc[mi][ni] = (f32x4){0.f, 0.f, 0.f, 0.f};

    bf16x8 A[2][4], Bf[2][8];

#define LOADK(KT, S)                                                            \
    {                                                                           \
        const unsigned short* ab = aws + (KT) * 4096;                           \
        const unsigned short* bb = bws + (KT) * 4096;                           \
        _Pragma("unroll")                                                       \
        for (int i = 0; i < 4; ++i) A[S][i] = ld16(ab + i * 512);               \
        _Pragma("unroll")                                                       \
        for (int n = 0; n < 8; ++n) Bf[S][n] = ld16(bb + n * 512);              \
    }                                                                           \
    __builtin_amdgcn_sched_barrier(0);
#define MM(S)                                                                   \
    __builtin_amdgcn_s_setprio(1);                                              \
    _Pragma("unroll")                                                           \
    for (int mi = 0; mi < 4; ++mi)                                              \
        _Pragma("unroll")                                                       \
        for (int ni = 0; ni < 8; ++ni)                                          \
            acc[mi][ni] = __builtin_amdgcn_mfma_f32_16x16x32_bf16(              \
                A[S][mi], Bf[S][ni], acc[mi][ni], 0, 0, 0);                     \
    __builtin_amdgcn_s_setprio(0);                                              \
    __builtin_amdgcn_sched_barrier(0);

    LOADK(0, 0)
    LOADK(1, 1)  MM(0)    // step 0
    LOADK(2, 0)  MM(1)    // step 1
    LOADK(3, 1)  MM(0)    // step 2
    LOADK(4, 0)  MM(1)    // step 3
    LOADK(5, 1)  MM(0)    // step 4
    LOADK(6, 0)  MM(1)    // step 5
    LOADK(7, 1)  MM(0)    // step 6
    LOADK(8, 0)  MM(1)    // step 7
    LOADK(9, 1)  MM(0)    // step 8
    LOADK(10, 0) MM(1)    // step 9
    LOADK(11, 1) MM(0)    // step 10
    LOADK(12, 0) MM(1)    // step 11
    LOADK(13, 1) MM(0)    // step 12
    LOADK(14, 0) MM(1)    // step 13
    LOADK(15, 1) MM(0)    // step 14
    MM(1)                 // step 15
#undef LOADK
#undef MM

    // biases
    const float* b1c = (bank ? nb1 : pb1) + c * HID;
    const float* b2c = (bank ? nb2 : pb2) + c * EMB;
    float b1v[8];
#pragma unroll
    for (int ni = 0; ni < 8; ++ni) b1v[ni] = b1c[ni * 16 + lr];

    // epilogue1: bias+relu -> Hs rows wave*64..+63 (swizzled); wave-private,
    // consumed only by this wave in GEMM2 -> no barrier needed.
#pragma unroll
    for (int mi = 0; mi < 4; ++mi) {
        int row0 = wave * 64 + mi * 16 + lkg * 4;
#pragma unroll
        for (int ni = 0; ni < 8; ++ni) {
            int col = ni * 16 + lr;
            int kgH = col >> 3, kin = col & 7;
#pragma unroll
            for (int j = 0; j < 4; ++j) {
                int r = row0 + j;
                float v = fmaxf(acc[mi][ni][j] + b1v[ni], 0.f);
                smem[r * 128 + ((kgH ^ (r & 7)) << 3) + kin] = f2b(v);
            }
        }
    }

    // W2 fragments (frag-packed, coalesced)
    const unsigned short* w2base = ws + WS_W2_OFF + (size_t)pair * 4096 + lane * 8;
    bf16x8 w2f[2][4];
#pragma unroll
    for (int k2 = 0; k2 < 4; ++k2)
#pragma unroll
        for (int ei = 0; ei < 2; ++ei)
            w2f[ei][k2] = ld16(w2base + k2 * 1024 + ei * 512);
    float b2v[2];
#pragma unroll
    for (int ei = 0; ei < 2; ++ei) b2v[ei] = b2c[ei * 16 + lr];

    // GEMM2: wave-private 64 rows x 32 EMB, K=128
    f32x4 acc2[4][2];
#pragma unroll
    for (int m2 = 0; m2 < 4; ++m2)
#pragma unroll
        for (int ei = 0; ei < 2; ++ei) acc2[m2][ei] = (f32x4){0.f, 0.f, 0.f, 0.f};
#pragma unroll
    for (int k2 = 0; k2 < 4; ++k2) {
        int kg = k2 * 4 + lkg;
        bf16x8 a2[4];
#pragma unroll
        for (int m2 = 0; m2 < 4; ++m2) {
            int r = wave * 64 + m2 * 16 + lr;
            a2[m2] = ld16(&smem[r * 128 + ((kg ^ (r & 7)) << 3)]);
        }
#pragma unroll
        for (int m2 = 0; m2 < 4; ++m2)
#pragma unroll
            for (int ei = 0; ei < 2; ++ei)
                acc2[m2][ei] = __builtin_amdgcn_mfma_f32_16x16x32_bf16(
                    a2[m2], w2f[ei][k2], acc2[m2][ei], 0, 0, 0);
    }

    float* outb = out + (size_t)bank * B_TOT * EMB * C_DIM;
#pragma unroll
    for (int m2 = 0; m2 < 4; ++m2) {
#pragma unroll
        for (int ei = 0; ei < 2; ++ei) {
            int e = ei * 16 + lr;
#pragma unroll
            for (int j = 0; j < 4; ++j) {
                int brow = bbase + wave * 64 + m2 * 16 + lkg * 4 + j;
                outb[((size_t)brow * EMB + e) * C_DIM + c] = acc2[m2][ei][j] + b2v[ei];
            }
        }
    }
}

// ===================== fallback (round-1 kernel, known-good) =====================
#define XS_LD 68
#define W1_LD 68
#define HS_LD 132
#define W2_LD 132
__device__ __forceinline__ bf16x8 load8u(const unsigned short* p) {
    union { unsigned long long q[2]; bf16x8 v; } u;
    u.q[0] = *(const unsigned long long*)(p);
    u.q[1] = *(const unsigned long long*)(p + 4);
    return u.v;
}
__global__ __launch_bounds__(256, 2) void bank_fallback(
    const float* __restrict__ x,
    const float* __restrict__ pW1, const float* __restrict__ pb1,
    const float* __restrict__ pW2, const float* __restrict__ pb2,
    const float* __restrict__ nW1, const float* __restrict__ nb1,
    const float* __restrict__ nW2, const float* __restrict__ nb2,
    float* __restrict__ out)
{
    __shared__ unsigned short Xs [128][XS_LD];
    __shared__ unsigned short W1T[HID][W1_LD];
    __shared__ unsigned short Hs [128][HS_LD];
    __shared__ unsigned short W2T[EMB][W2_LD];
    int p = blockIdx.x;
    int xcd = p & 7, rank = p >> 3;
    int c = xcd * 16 + (rank & 15);
    int btile = (rank >> 4) & 7;
    int bank = rank >> 7;
    int bbase = btile * 128;
    const float* W1c = (bank ? nW1 : pW1) + (size_t)c * IN_DIM * HID;
    const float* b1c = (bank ? nb1 : pb1) + c * HID;
    const float* W2c = (bank ? nW2 : pW2) + (size_t)c * HID * EMB;
    const float* b2c = (bank ? nb2 : pb2) + c * EMB;
    float* outb = out + (size_t)bank * B_TOT * EMB * C_DIM;
    int t = threadIdx.x, wave = t >> 6, lane = t & 63;
    int lr = lane & 15, lkg = lane >> 4, wm = wave >> 1, wn = wave & 1;
    {
        int e0 = (t & 7) * 4, h0 = (t >> 3) * 4;
        f32x4 L0 = *(const f32x4*)&W2c[(h0 + 0) * EMB + e0];
        f32x4 L1 = *(const f32x4*)&W2c[(h0 + 1) * EMB + e0];
        f32x4 L2 = *(const f32x4*)&W2c[(h0 + 2) * EMB + e0];
        f32x4 L3 = *(const f32x4*)&W2c[(h0 + 3) * EMB + e0];
#pragma unroll
        for (int j = 0; j < 4; ++j)
            *(unsigned long long*)&W2T[e0 + j][h0] = pack4(L0[j], L1[j], L2[j], L3[j]);
    }
    float b1v[4];
#pragma unroll
    for (int ni = 0; ni < 4; ++ni) b1v[ni] = b1c[wn * 64 + ni * 16 + lr];
    float b2v[2];
#pragma unroll
    for (int ei = 0; ei < 2; ++ei) b2v[ei] = b2c[ei * 16 + lr];
    f32x4 acc[4][4];
#pragma unroll
    for (int mi = 0; mi < 4; ++mi)
#pragma unroll
        for (int ni = 0; ni < 4; ++ni) acc[mi][ni] = (f32x4){0.f, 0.f, 0.f, 0.f};
    for (int kt = 0; kt < 8; ++kt) {
        int kb = kt * 64;
#pragma unroll
        for (int w8 = 0; w8 < 8; ++w8) {
            int f = w8 * 256 + t;
            int row = f >> 4, col = (f & 15) * 4;
            f32x4 v = *(const f32x4*)&x[(size_t)(bbase + row) * IN_DIM + kb + col];
            *(unsigned long long*)&Xs[row][col] = pack4(v[0], v[1], v[2], v[3]);
        }
#pragma unroll
        for (int g = 0; g < 2; ++g) {
            int s = g * 256 + t;
            int k0 = (s >> 5) * 4, h0 = (s & 31) * 4;
            const float* src = &W1c[(size_t)(kb + k0) * HID + h0];
            f32x4 L0 = *(const f32x4*)(src + 0 * HID);
            f32x4 L1 = *(const f32x4*)(src + 1 * HID);
            f32x4 L2 = *(const f32x4*)(src + 2 * HID);
            f32x4 L3 = *(const f32x4*)(src + 3 * HID);
#pragma unroll
            for (int j = 0; j < 4; ++j)
                *(unsigned long long*)&W1T[h0 + j][k0] = pack4(L0[j], L1[j], L2[j], L3[j]);
        }
        __syncthreads();
#pragma unroll
        for (int ki = 0; ki < 2; ++ki) {
            int kcol = ki * 32 + lkg * 8;
            bf16x8 af[4], bfr[4];
#pragma unroll
            for (int mi = 0; mi < 4; ++mi) af[mi] = load8u(&Xs[wm * 64 + mi * 16 + lr][kcol]);
#pragma unroll
            for (int ni = 0; ni < 4; ++ni) bfr[ni] = load8u(&W1T[wn * 64 + ni * 16 + lr][kcol]);
#pragma unroll
            for (int mi = 0; mi < 4; ++mi)
#pragma unroll
                for (int ni = 0; ni < 4; ++ni)
                    acc[mi][ni] = __builtin_amdgcn_mfma_f32_16x16x32_bf16(
                        af[mi], bfr[ni], acc[mi][ni], 0, 0, 0);
        }
        __syncthreads();
    }
#pragma unroll
    for (int mi = 0; mi < 4; ++mi) {
        int row = wm * 64 + mi * 16 + lkg * 4;
#pragma unroll
        for (int ni = 0; ni < 4; ++ni) {
            int col = wn * 64 + ni * 16 + lr;
#pragma unroll
            for (int j = 0; j < 4; ++j)
                Hs[row + j][col] = f2b(fmaxf(acc[mi][ni][j] + b1v[ni], 0.f));
        }
    }
    __syncthreads();
    f32x4 acc2[2][2];
#pragma unroll
    for (int m2 = 0; m2 < 2; ++m2)
#pragma unroll
        for (int ei = 0; ei < 2; ++ei) acc2[m2][ei] = (f32x4){0.f, 0.f, 0.f, 0.f};
    int rb = wave * 32;
#pragma unroll
    for (int k2 = 0; k2 < 4; ++k2) {
        int kcol = k2 * 32 + lkg * 8;
        bf16x8 a2[2], b2f[2];
#pragma unroll
        for (int m2 = 0; m2 < 2; ++m2) a2[m2] = load8u(&Hs[rb + m2 * 16 + lr][kcol]);
#pragma unroll
        for (int ei = 0; ei < 2; ++ei) b2f[ei] = load8u(&W2T[ei * 16 + lr][kcol]);
#pragma unroll
        for (int m2 = 0; m2 < 2; ++m2)
#pragma unroll
            for (int ei = 0; ei < 2; ++ei)
                acc2[m2][ei] = __builtin_amdgcn_mfma_f32_16x16x32_bf16(
                    a2[m2], b2f[ei], acc2[m2][ei], 0, 0, 0);
    }
#pragma unroll
    for (int m2 = 0; m2 < 2; ++m2)
#pragma unroll
        for (int ei = 0; ei < 2; ++ei) {
            int e = ei * 16 + lr;
#pragma unroll
            for (int j = 0; j < 4; ++j) {
                int brow = bbase + rb + m2 * 16 + lkg * 4 + j;
                outb[((size_t)brow * EMB + e) * C_DIM + c] = acc2[m2][ei][j] + b2v[ei];
            }
        }
}

extern "C" void kernel_launch(void* const* d_in, const int* in_sizes, int n_in,
                              void* d_out, int out_size, void* d_ws, size_t ws_size,
                              hipStream_t stream) {
    const float* x   = (const float*)d_in[0];
    const float* pW1 = (const float*)d_in[1];
    const float* pb1 = (const float*)d_in[2];
    const float* pW2 = (const float*)d_in[3];
    const float* pb2 = (const float*)d_in[4];
    const float* nW1 = (const float*)d_in[5];
    const float* nb1 = (const float*)d_in[6];
    const float* nW2 = (const float*)d_in[7];
    const float* nb2 = (const float*)d_in[8];
    float* out = (float*)d_out;

    if (ws_size >= WS_NEEDED_B) {
        unsigned short* ws = (unsigned short*)d_ws;
        prepass<<<dim3(1024), dim3(256), 0, stream>>>(x, pW1, pW2, nW1, nW2, ws);
        bank_main<<<dim3(1024), dim3(256), 0, stream>>>(pb1, pb2, nb1, nb2, ws, out);
    } else {
        bank_fallback<<<dim3(2048), dim3(256), 0, stream>>>(
            x, pW1, pb1, pW2, pb2, nW1, nb1, nW2, nb2, out);
    }
}